// Round 2
// baseline (530.936 us; speedup 1.0000x reference)
//
#include <hip/hip_runtime.h>
#include <hip/hip_bf16.h>
#include <stdint.h>

// MoE FFN: B=2,T=2048,D=1024,F=4096,E=8,K=2. S=4096 tokens, 8192 assignments.
#define S_TOK 4096
#define DDIM  1024
#define FDIM  4096
#define EEXP  8
#define CAP   (S_TOK * 2 + 128)   // assignment arena capacity (8192 + tile pad)

typedef __bf16 bf16x8 __attribute__((ext_vector_type(8)));
typedef float  f32x4  __attribute__((ext_vector_type(4)));
typedef unsigned short us4 __attribute__((ext_vector_type(4)));

__device__ __forceinline__ unsigned short f2bf(float f) {
    union { float f; unsigned u; } v; v.f = f;
    unsigned u = v.u;
    return (unsigned short)((u + 0x7FFFu + ((u >> 16) & 1u)) >> 16);  // RNE
}

// global -> LDS async copy, 16B per lane. LDS dest = wave-uniform base + lane*16.
__device__ __forceinline__ void gload16(const void* g, void* l) {
    auto gp = reinterpret_cast<const __attribute__((address_space(1))) uint32_t*>(
        reinterpret_cast<uintptr_t>(g));
    auto lp = reinterpret_cast<__attribute__((address_space(3))) uint32_t*>(
        static_cast<uint32_t>(reinterpret_cast<uintptr_t>(l)));
    __builtin_amdgcn_global_load_lds(gp, lp, 16, 0, 0);
}

// ---------------- small kernels ----------------

__global__ void zero_k(int* p, int n) {
    int i = threadIdx.x;
    if (i < n) p[i] = 0;
}

__global__ void cvt_bf16(const float* __restrict__ src, unsigned short* __restrict__ dst, int n4) {
    int stride = gridDim.x * blockDim.x;
    for (int i = blockIdx.x * blockDim.x + threadIdx.x; i < n4; i += stride) {
        float4 v = ((const float4*)src)[i];
        us4 o;
        o[0] = f2bf(v.x); o[1] = f2bf(v.y); o[2] = f2bf(v.z); o[3] = f2bf(v.w);
        ((us4*)dst)[i] = o;
    }
}

// Router: one wave per token, fp32 dot products (must match numpy top-2 selection).
__global__ void router_k(const float* __restrict__ x, const float* __restrict__ gw,
                         int* __restrict__ topk_e, float* __restrict__ topk_g,
                         int* __restrict__ counts) {
    int s = blockIdx.x;
    int l = threadIdx.x;
    const float* xr = x + (size_t)s * DDIM;
    float acc[EEXP];
#pragma unroll
    for (int e = 0; e < EEXP; ++e) acc[e] = 0.f;
    for (int i = 0; i < DDIM; i += 64) {
        float xv = xr[i + l];
#pragma unroll
        for (int e = 0; e < EEXP; ++e) acc[e] = fmaf(xv, gw[e * DDIM + i + l], acc[e]);
    }
#pragma unroll
    for (int e = 0; e < EEXP; ++e)
        for (int off = 32; off > 0; off >>= 1) acc[e] += __shfl_down(acc[e], off, 64);
    if (l == 0) {
        float v0 = -1e30f, v1 = -1e30f; int i0 = 0, i1 = 0;
#pragma unroll
        for (int e = 0; e < EEXP; ++e) {
            float v = acc[e];
            if (v > v0)      { v1 = v0; i1 = i0; v0 = v; i0 = e; }
            else if (v > v1) { v1 = v;  i1 = e; }
        }
        float t = expf(v1 - v0);
        float d = 1.f + t;
        topk_e[2 * s] = i0; topk_e[2 * s + 1] = i1;
        topk_g[2 * s] = 1.f / d; topk_g[2 * s + 1] = t / d;
        atomicAdd(&counts[i0], 1);
        atomicAdd(&counts[i1], 1);
    }
}

__global__ void scan_k(const int* __restrict__ counts, int* __restrict__ basep) {
    if (threadIdx.x == 0) {
        int b = 0;
        for (int e = 0; e < EEXP; ++e) { basep[e] = b; b += counts[e]; }
    }
}

__global__ void scatter_k(const int* __restrict__ topk_e, int* __restrict__ rankctr,
                          const int* __restrict__ basep, int* __restrict__ arena_token,
                          int* __restrict__ pos_of) {
    int s = blockIdx.x * blockDim.x + threadIdx.x;
    if (s >= S_TOK) return;
#pragma unroll
    for (int t = 0; t < 2; ++t) {
        int e = topk_e[2 * s + t];
        int r = atomicAdd(&rankctr[e], 1);
        int p = basep[e] + r;
        arena_token[p] = s;
        pos_of[2 * s + t] = p;
    }
}

// ---------------- MFMA GEMM (128x128 tile, BK=32, 4 waves, T2 swizzle, T1 XCD swizzle) ----
// C[m][n] = sum_k A[m][k] * B[n][k]   (both K-contiguous row-major, "BT" layout)
// LDS swizzle (rule 21, both-sides): linear gload_lds dest; LDS byte d holds
// orig(row=d>>6, chunk=(d>>4&3) ^ ((d>>7)&3)). Write side: per-lane source chunk
// = (l&3) ^ ((l>>3)&3) (lane-pure). Read side: chunk' = (l>>4) ^ (((l&15)>>1)&3).
// EPI==1: A rows gathered via arena_token from xb; out = relu(acc + b1) -> hA (bf16)
// EPI==2: A rows contiguous in hA arena; out = acc -> outA (fp32)
template <int EPI>
__global__ __launch_bounds__(256, 2) void moe_gemm(
    const unsigned short* __restrict__ Asrc, const unsigned short* __restrict__ Bw,
    const float* __restrict__ bias, unsigned short* __restrict__ hOut,
    float* __restrict__ fOut, const int* __restrict__ arena_token,
    const int* __restrict__ counts, const int* __restrict__ basep, int Kd, int Nd,
    int nx, int ny) {
    // T1: bijective XCD swizzle over 1D grid (gridDim.x % 8 == 0 by construction).
    // Work order n-major: wid = (n*E + e)*ny + m  -> each XCD chunk spans all experts.
    int cpx = gridDim.x >> 3;
    int bid = blockIdx.x;
    int wid = (bid & 7) * cpx + (bid >> 3);
    int my  = wid % ny;
    int ne  = wid / ny;
    int e   = ne % EEXP;
    int n   = ne / EEXP;

    int count = counts[e];
    int m0 = my * 128;
    if (m0 >= count) return;
    int base = basep[e];
    int n0 = n * 128;
    int tid = threadIdx.x, w = tid >> 6, l = tid & 63;

    __shared__ unsigned short lsA[128 * 32];
    __shared__ unsigned short lsB[128 * 32];

    int src_chunk = ((l & 3) ^ ((l >> 3) & 3)) * 8;   // swizzled source k-offset (elements)
    const unsigned short* pA[2];
    const unsigned short* pB[2];
#pragma unroll
    for (int i = 0; i < 2; ++i) {
        int r = i * 64 + w * 16 + (l >> 2);
        int gr = m0 + r;
        if (EPI == 1) {
            int rr = (gr < count) ? gr : (count - 1);
            int tok = arena_token[base + rr];
            pA[i] = Asrc + (size_t)tok * Kd + src_chunk;
        } else {
            pA[i] = Asrc + (size_t)(base + gr) * Kd + src_chunk;  // < CAP rows; masked at store
        }
        pB[i] = Bw + ((size_t)e * Nd + n0 + r) * Kd + src_chunk;
    }
    char* dA = (char*)lsA + w * 1024;
    char* dB = (char*)lsB + w * 1024;
    int wm = w >> 1, wn = w & 1;
    int rd_chunk = ((l >> 4) ^ (((l & 15) >> 1) & 3)) * 16;  // swizzled read chunk (bytes)
    const char* aB = (const char*)lsA + (size_t)(wm * 64 + (l & 15)) * 64 + rd_chunk;
    const char* bB = (const char*)lsB + (size_t)(wn * 64 + (l & 15)) * 64 + rd_chunk;

    f32x4 acc[4][4];
#pragma unroll
    for (int i = 0; i < 4; ++i)
#pragma unroll
        for (int j = 0; j < 4; ++j) acc[i][j] = (f32x4){0.f, 0.f, 0.f, 0.f};

    for (int k0 = 0; k0 < Kd; k0 += 32) {
        gload16(pA[0] + k0, dA);
        gload16(pA[1] + k0, dA + 4096);
        gload16(pB[0] + k0, dB);
        gload16(pB[1] + k0, dB + 4096);
        __syncthreads();
        bf16x8 af[4], bfr[4];
#pragma unroll
        for (int mi = 0; mi < 4; ++mi) af[mi] = *(const bf16x8*)(aB + mi * 1024);
#pragma unroll
        for (int ni = 0; ni < 4; ++ni) bfr[ni] = *(const bf16x8*)(bB + ni * 1024);
#pragma unroll
        for (int mi = 0; mi < 4; ++mi)
#pragma unroll
            for (int ni = 0; ni < 4; ++ni)
                acc[mi][ni] = __builtin_amdgcn_mfma_f32_16x16x32_bf16(af[mi], bfr[ni], acc[mi][ni], 0, 0, 0);
        __syncthreads();
    }

    // Epilogue. C/D layout: col = lane&15, row = (lane>>4)*4 + reg  [m89 verified]
#pragma unroll
    for (int mi = 0; mi < 4; ++mi)
#pragma unroll
        for (int ni = 0; ni < 4; ++ni)
#pragma unroll
            for (int r = 0; r < 4; ++r) {
                int rl = wm * 64 + mi * 16 + (l >> 4) * 4 + r;
                int gr = m0 + rl;
                if (gr < count) {
                    int col = n0 + wn * 64 + ni * 16 + (l & 15);
                    float v = acc[mi][ni][r];
                    if (EPI == 1) {
                        v += bias[e * Nd + col];
                        v = fmaxf(v, 0.f);
                        hOut[(size_t)(base + gr) * Nd + col] = f2bf(v);
                    } else {
                        fOut[(size_t)(base + gr) * Nd + col] = v;
                    }
                }
            }
}

// Deterministic combine: y[s] = g0*(out[p0]+b2[e0]) + g1*(out[p1]+b2[e1])
__global__ void combine_k(const float* __restrict__ outA, const float* __restrict__ b2,
                          const int* __restrict__ topk_e, const float* __restrict__ topk_g,
                          const int* __restrict__ pos_of, float* __restrict__ y) {
    int idx = blockIdx.x * blockDim.x + threadIdx.x;  // S*D/4 threads
    int s = idx >> 8;            // D/4 = 256
    int c = (idx & 255) * 4;
    int e0 = topk_e[2 * s], e1 = topk_e[2 * s + 1];
    float g0 = topk_g[2 * s], g1 = topk_g[2 * s + 1];
    int p0 = pos_of[2 * s], p1 = pos_of[2 * s + 1];
    float4 o0 = *(const float4*)(outA + (size_t)p0 * DDIM + c);
    float4 o1 = *(const float4*)(outA + (size_t)p1 * DDIM + c);
    float4 c0 = *(const float4*)(b2 + (size_t)e0 * DDIM + c);
    float4 c1 = *(const float4*)(b2 + (size_t)e1 * DDIM + c);
    float4 r;
    r.x = g0 * (o0.x + c0.x) + g1 * (o1.x + c1.x);
    r.y = g0 * (o0.y + c0.y) + g1 * (o1.y + c1.y);
    r.z = g0 * (o0.z + c0.z) + g1 * (o1.z + c1.z);
    r.w = g0 * (o0.w + c0.w) + g1 * (o1.w + c1.w);
    *(float4*)(y + (size_t)s * DDIM + c) = r;
}

extern "C" void kernel_launch(void* const* d_in, const int* in_sizes, int n_in,
                              void* d_out, int out_size, void* d_ws, size_t ws_size,
                              hipStream_t stream) {
    const float* x      = (const float*)d_in[0];
    const float* gate_w = (const float*)d_in[1];
    const float* w1     = (const float*)d_in[2];
    const float* b1     = (const float*)d_in[3];
    const float* w2     = (const float*)d_in[4];
    const float* b2     = (const float*)d_in[5];
    // d_in[6] = k (==2), compile-time constant here.

    char* p = (char*)d_ws;
    unsigned short* w1b = (unsigned short*)p; p += (size_t)EEXP * FDIM * DDIM * 2;  // 64 MB
    unsigned short* w2b = (unsigned short*)p; p += (size_t)EEXP * FDIM * DDIM * 2;  // 64 MB
    unsigned short* xb  = (unsigned short*)p; p += (size_t)S_TOK * DDIM * 2;        //  8 MB
    unsigned short* hA  = (unsigned short*)p; p += (size_t)CAP * FDIM * 2;          // 65 MB
    float* outA         = (float*)p;          p += (size_t)CAP * DDIM * 4;          // 32.5 MB
    int*   topk_e       = (int*)p;            p += S_TOK * 2 * 4;
    float* topk_g       = (float*)p;          p += S_TOK * 2 * 4;
    int*   pos_of       = (int*)p;            p += S_TOK * 2 * 4;
    int*   arena_token  = (int*)p;            p += CAP * 4;
    int*   counts       = (int*)p;            p += 64;
    int*   rankctr      = (int*)p;            p += 64;
    int*   basep        = (int*)p;            p += 64;
    (void)ws_size; (void)in_sizes; (void)n_in; (void)out_size;

    zero_k<<<1, 64, 0, stream>>>(counts, 48);  // counts + rankctr + basep (contiguous)

    cvt_bf16<<<2048, 256, 0, stream>>>(w1, w1b, EEXP * FDIM * DDIM / 4);
    cvt_bf16<<<2048, 256, 0, stream>>>(w2, w2b, EEXP * FDIM * DDIM / 4);
    cvt_bf16<<<512, 256, 0, stream>>>(x, xb, S_TOK * DDIM / 4);

    router_k<<<S_TOK, 64, 0, stream>>>(x, gate_w, topk_e, topk_g, counts);
    scan_k<<<1, 1, 0, stream>>>(counts, basep);
    scatter_k<<<S_TOK / 256, 256, 0, stream>>>(topk_e, rankctr, basep, arena_token, pos_of);

    // 1D grids (blocks = nx * ny * E, divisible by 8 for the XCD swizzle)
    moe_gemm<1><<<dim3((FDIM / 128) * 32 * EEXP), 256, 0, stream>>>(
        xb, w1b, b1, hA, nullptr, arena_token, counts, basep, DDIM, FDIM, FDIM / 128, 32);
    moe_gemm<2><<<dim3((DDIM / 128) * 32 * EEXP), 256, 0, stream>>>(
        hA, w2b, nullptr, nullptr, outA, arena_token, counts, basep, FDIM, DDIM, DDIM / 128, 32);

    combine_k<<<S_TOK * DDIM / 4 / 256, 256, 0, stream>>>(
        outA, b2, topk_e, topk_g, pos_of, (float*)d_out);
}

// Round 3
// 521.645 us; speedup vs baseline: 1.0178x; 1.0178x over previous
//
#include <hip/hip_runtime.h>
#include <hip/hip_bf16.h>
#include <stdint.h>

// MoE FFN: B=2,T=2048,D=1024,F=4096,E=8,K=2. S=4096 tokens, 8192 assignments.
#define S_TOK 4096
#define DDIM  1024
#define FDIM  4096
#define EEXP  8
#define CAP   (S_TOK * 2 + 128)   // assignment arena capacity (8192 + tile pad)

typedef __bf16 bf16x8 __attribute__((ext_vector_type(8)));
typedef float  f32x4  __attribute__((ext_vector_type(4)));
typedef unsigned short us4 __attribute__((ext_vector_type(4)));

__device__ __forceinline__ unsigned short f2bf(float f) {
    union { float f; unsigned u; } v; v.f = f;
    unsigned u = v.u;
    return (unsigned short)((u + 0x7FFFu + ((u >> 16) & 1u)) >> 16);  // RNE
}

// global -> LDS async copy, 16B per lane. LDS dest = wave-uniform base + lane*16.
__device__ __forceinline__ void gload16(const void* g, void* l) {
    auto gp = reinterpret_cast<const __attribute__((address_space(1))) uint32_t*>(
        reinterpret_cast<uintptr_t>(g));
    auto lp = reinterpret_cast<__attribute__((address_space(3))) uint32_t*>(
        static_cast<uint32_t>(reinterpret_cast<uintptr_t>(l)));
    __builtin_amdgcn_global_load_lds(gp, lp, 16, 0, 0);
}

// ---------------- small kernels ----------------

__global__ void zero_k(int* p, int n) {
    int i = threadIdx.x;
    if (i < n) p[i] = 0;
}

__global__ void cvt_bf16(const float* __restrict__ src, unsigned short* __restrict__ dst, int n4) {
    int stride = gridDim.x * blockDim.x;
    for (int i = blockIdx.x * blockDim.x + threadIdx.x; i < n4; i += stride) {
        float4 v = ((const float4*)src)[i];
        us4 o;
        o[0] = f2bf(v.x); o[1] = f2bf(v.y); o[2] = f2bf(v.z); o[3] = f2bf(v.w);
        ((us4*)dst)[i] = o;
    }
}

// Router: one wave per token, fp32 dot products (must match numpy top-2 selection).
// Also emits the bf16 copy of x (fused, saves a separate cvt dispatch).
__global__ void router_k(const float* __restrict__ x, const float* __restrict__ gw,
                         unsigned short* __restrict__ xb,
                         int* __restrict__ topk_e, float* __restrict__ topk_g,
                         int* __restrict__ counts) {
    int s = blockIdx.x;
    int l = threadIdx.x;
    const float* xr = x + (size_t)s * DDIM;
    unsigned short* xbr = xb + (size_t)s * DDIM;
    float acc[EEXP];
#pragma unroll
    for (int e = 0; e < EEXP; ++e) acc[e] = 0.f;
    for (int i = 0; i < DDIM; i += 64) {
        float xv = xr[i + l];
        xbr[i + l] = f2bf(xv);
#pragma unroll
        for (int e = 0; e < EEXP; ++e) acc[e] = fmaf(xv, gw[e * DDIM + i + l], acc[e]);
    }
#pragma unroll
    for (int e = 0; e < EEXP; ++e)
        for (int off = 32; off > 0; off >>= 1) acc[e] += __shfl_down(acc[e], off, 64);
    if (l == 0) {
        float v0 = -1e30f, v1 = -1e30f; int i0 = 0, i1 = 0;
#pragma unroll
        for (int e = 0; e < EEXP; ++e) {
            float v = acc[e];
            if (v > v0)      { v1 = v0; i1 = i0; v0 = v; i0 = e; }
            else if (v > v1) { v1 = v;  i1 = e; }
        }
        float t = expf(v1 - v0);
        float d = 1.f + t;
        topk_e[2 * s] = i0; topk_e[2 * s + 1] = i1;
        topk_g[2 * s] = 1.f / d; topk_g[2 * s + 1] = t / d;
        atomicAdd(&counts[i0], 1);
        atomicAdd(&counts[i1], 1);
    }
}

__global__ void scan_k(const int* __restrict__ counts, int* __restrict__ basep) {
    if (threadIdx.x == 0) {
        int b = 0;
        for (int e = 0; e < EEXP; ++e) { basep[e] = b; b += counts[e]; }
    }
}

__global__ void scatter_k(const int* __restrict__ topk_e, int* __restrict__ rankctr,
                          const int* __restrict__ basep, int* __restrict__ arena_token,
                          int* __restrict__ pos_of) {
    int s = blockIdx.x * blockDim.x + threadIdx.x;
    if (s >= S_TOK) return;
#pragma unroll
    for (int t = 0; t < 2; ++t) {
        int e = topk_e[2 * s + t];
        int r = atomicAdd(&rankctr[e], 1);
        int p = basep[e] + r;
        arena_token[p] = s;
        pos_of[2 * s + t] = p;
    }
}

// ---------------- MFMA GEMM: 128x128 tile, BK=32, 4 waves, T3-min dbuf K-loop ----------
// C[m][n] = sum_k A[m][k] * B[n][k]   (both K-contiguous row-major, "BT" layout)
// T2 swizzle (rule 21, both-sides): linear gload_lds dest; per-lane SOURCE chunk
// = (l&3) ^ ((l>>3)&3); read chunk' = (l>>4) ^ (((l&15)>>1)&3). Conflict-free (r2 PMC: 0).
// T3-min schedule (guide §5.5 T3 recipe): double-buffered LDS; per iter
//   STAGE(buf[b^1], t+1); ds_read buf[b]; MFMA; __syncthreads()  // = vmcnt(0)+barrier
// One barrier per K-step; load latency hides under current tile's ds_read+MFMA.
// EPI==1: A rows gathered via arena_token from xb; out = relu(acc + b1) -> hA (bf16)
// EPI==2: A rows contiguous in hA arena; out = acc -> outA (fp32)
template <int EPI>
__global__ __launch_bounds__(256, 2) void moe_gemm(
    const unsigned short* __restrict__ Asrc, const unsigned short* __restrict__ Bw,
    const float* __restrict__ bias, unsigned short* __restrict__ hOut,
    float* __restrict__ fOut, const int* __restrict__ arena_token,
    const int* __restrict__ counts, const int* __restrict__ basep, int Kd, int Nd,
    int nx, int ny) {
    // T1: bijective XCD swizzle over 1D grid (gridDim.x % 8 == 0 by construction).
    // Work order n-major: wid = (n*E + e)*ny + m  -> each XCD chunk spans all experts.
    int cpx = gridDim.x >> 3;
    int bid = blockIdx.x;
    int wid = (bid & 7) * cpx + (bid >> 3);
    int my  = wid % ny;
    int ne  = wid / ny;
    int e   = ne % EEXP;
    int n   = ne / EEXP;

    int count = counts[e];
    int m0 = my * 128;
    if (m0 >= count) return;
    int base = basep[e];
    int n0 = n * 128;
    int tid = threadIdx.x, w = tid >> 6, l = tid & 63;

    // buf b at smem + b*16384: A at +0 (8KB), B at +8192 (8KB)
    __shared__ char smem[32768];

    int src_chunk = ((l & 3) ^ ((l >> 3) & 3)) * 8;   // swizzled source k-offset (elements)
    const unsigned short* pA[2];
    const unsigned short* pB[2];
#pragma unroll
    for (int i = 0; i < 2; ++i) {
        int r = i * 64 + w * 16 + (l >> 2);
        int gr = m0 + r;
        if (EPI == 1) {
            int rr = (gr < count) ? gr : (count - 1);
            int tok = arena_token[base + rr];
            pA[i] = Asrc + (size_t)tok * Kd + src_chunk;
        } else {
            pA[i] = Asrc + (size_t)(base + gr) * Kd + src_chunk;  // < CAP rows; masked at store
        }
        pB[i] = Bw + ((size_t)e * Nd + n0 + r) * Kd + src_chunk;
    }
    int wm = w >> 1, wn = w & 1;
    int rd_chunk = ((l >> 4) ^ (((l & 15) >> 1) & 3)) * 16;  // swizzled read chunk (bytes)
    int aoff = (wm * 64 + (l & 15)) * 64 + rd_chunk;
    int boff = 8192 + (wn * 64 + (l & 15)) * 64 + rd_chunk;
    int doff = w * 1024;

    f32x4 acc[4][4];
#pragma unroll
    for (int i = 0; i < 4; ++i)
#pragma unroll
        for (int j = 0; j < 4; ++j) acc[i][j] = (f32x4){0.f, 0.f, 0.f, 0.f};

    int nt = Kd >> 5;
    // prologue: stage tile 0 into buf 0
    {
        char* dA = smem + doff;
        char* dB = smem + 8192 + doff;
        gload16(pA[0], dA);
        gload16(pA[1], dA + 4096);
        gload16(pB[0], dB);
        gload16(pB[1], dB + 4096);
    }
    __syncthreads();

    for (int t = 0; t < nt; ++t) {
        int b = t & 1;
        if (t + 1 < nt) {
            int k1 = (t + 1) << 5;
            char* dA = smem + (b ^ 1) * 16384 + doff;
            char* dB = smem + (b ^ 1) * 16384 + 8192 + doff;
            gload16(pA[0] + k1, dA);
            gload16(pA[1] + k1, dA + 4096);
            gload16(pB[0] + k1, dB);
            gload16(pB[1] + k1, dB + 4096);
        }
        const char* aB = smem + b * 16384 + aoff;
        const char* bB = smem + b * 16384 + boff;
        bf16x8 af[4], bfr[4];
#pragma unroll
        for (int mi = 0; mi < 4; ++mi) af[mi] = *(const bf16x8*)(aB + mi * 1024);
#pragma unroll
        for (int ni = 0; ni < 4; ++ni) bfr[ni] = *(const bf16x8*)(bB + ni * 1024);
#pragma unroll
        for (int mi = 0; mi < 4; ++mi)
#pragma unroll
            for (int ni = 0; ni < 4; ++ni)
                acc[mi][ni] = __builtin_amdgcn_mfma_f32_16x16x32_bf16(af[mi], bfr[ni], acc[mi][ni], 0, 0, 0);
        __syncthreads();  // vmcnt(0)+lgkmcnt(0)+barrier: orders reads of buf[b] before next STAGE into it
    }

    // Epilogue. C/D layout: col = lane&15, row = (lane>>4)*4 + reg  [m89 verified]
#pragma unroll
    for (int mi = 0; mi < 4; ++mi)
#pragma unroll
        for (int ni = 0; ni < 4; ++ni)
#pragma unroll
            for (int r = 0; r < 4; ++r) {
                int rl = wm * 64 + mi * 16 + (l >> 4) * 4 + r;
                int gr = m0 + rl;
                if (gr < count) {
                    int col = n0 + wn * 64 + ni * 16 + (l & 15);
                    float v = acc[mi][ni][r];
                    if (EPI == 1) {
                        v += bias[e * Nd + col];
                        v = fmaxf(v, 0.f);
                        hOut[(size_t)(base + gr) * Nd + col] = f2bf(v);
                    } else {
                        fOut[(size_t)(base + gr) * Nd + col] = v;
                    }
                }
            }
}

// Deterministic combine: y[s] = g0*(out[p0]+b2[e0]) + g1*(out[p1]+b2[e1])
__global__ void combine_k(const float* __restrict__ outA, const float* __restrict__ b2,
                          const int* __restrict__ topk_e, const float* __restrict__ topk_g,
                          const int* __restrict__ pos_of, float* __restrict__ y) {
    int idx = blockIdx.x * blockDim.x + threadIdx.x;  // S*D/4 threads
    int s = idx >> 8;            // D/4 = 256
    int c = (idx & 255) * 4;
    int e0 = topk_e[2 * s], e1 = topk_e[2 * s + 1];
    float g0 = topk_g[2 * s], g1 = topk_g[2 * s + 1];
    int p0 = pos_of[2 * s], p1 = pos_of[2 * s + 1];
    float4 o0 = *(const float4*)(outA + (size_t)p0 * DDIM + c);
    float4 o1 = *(const float4*)(outA + (size_t)p1 * DDIM + c);
    float4 c0 = *(const float4*)(b2 + (size_t)e0 * DDIM + c);
    float4 c1 = *(const float4*)(b2 + (size_t)e1 * DDIM + c);
    float4 r;
    r.x = g0 * (o0.x + c0.x) + g1 * (o1.x + c1.x);
    r.y = g0 * (o0.y + c0.y) + g1 * (o1.y + c1.y);
    r.z = g0 * (o0.z + c0.z) + g1 * (o1.z + c1.z);
    r.w = g0 * (o0.w + c0.w) + g1 * (o1.w + c1.w);
    *(float4*)(y + (size_t)s * DDIM + c) = r;
}

extern "C" void kernel_launch(void* const* d_in, const int* in_sizes, int n_in,
                              void* d_out, int out_size, void* d_ws, size_t ws_size,
                              hipStream_t stream) {
    const float* x      = (const float*)d_in[0];
    const float* gate_w = (const float*)d_in[1];
    const float* w1     = (const float*)d_in[2];
    const float* b1     = (const float*)d_in[3];
    const float* w2     = (const float*)d_in[4];
    const float* b2     = (const float*)d_in[5];
    // d_in[6] = k (==2), compile-time constant here.

    char* p = (char*)d_ws;
    unsigned short* w1b = (unsigned short*)p; p += (size_t)EEXP * FDIM * DDIM * 2;  // 64 MB
    unsigned short* w2b = (unsigned short*)p; p += (size_t)EEXP * FDIM * DDIM * 2;  // 64 MB
    unsigned short* xb  = (unsigned short*)p; p += (size_t)S_TOK * DDIM * 2;        //  8 MB
    unsigned short* hA  = (unsigned short*)p; p += (size_t)CAP * FDIM * 2;          // 65 MB
    float* outA         = (float*)p;          p += (size_t)CAP * DDIM * 4;          // 32.5 MB
    int*   topk_e       = (int*)p;            p += S_TOK * 2 * 4;
    float* topk_g       = (float*)p;          p += S_TOK * 2 * 4;
    int*   pos_of       = (int*)p;            p += S_TOK * 2 * 4;
    int*   arena_token  = (int*)p;            p += CAP * 4;
    int*   counts       = (int*)p;            p += 64;
    int*   rankctr      = (int*)p;            p += 64;
    int*   basep        = (int*)p;            p += 64;
    (void)ws_size; (void)in_sizes; (void)n_in; (void)out_size;

    zero_k<<<1, 64, 0, stream>>>(counts, 48);  // counts + rankctr + basep (contiguous)

    cvt_bf16<<<2048, 256, 0, stream>>>(w1, w1b, EEXP * FDIM * DDIM / 4);
    cvt_bf16<<<2048, 256, 0, stream>>>(w2, w2b, EEXP * FDIM * DDIM / 4);

    router_k<<<S_TOK, 64, 0, stream>>>(x, gate_w, xb, topk_e, topk_g, counts);
    scan_k<<<1, 1, 0, stream>>>(counts, basep);
    scatter_k<<<S_TOK / 256, 256, 0, stream>>>(topk_e, rankctr, basep, arena_token, pos_of);

    // 1D grids (blocks = nx * ny * E, divisible by 8 for the XCD swizzle)
    moe_gemm<1><<<dim3((FDIM / 128) * 32 * EEXP), 256, 0, stream>>>(
        xb, w1b, b1, hA, nullptr, arena_token, counts, basep, DDIM, FDIM, FDIM / 128, 32);
    moe_gemm<2><<<dim3((DDIM / 128) * 32 * EEXP), 256, 0, stream>>>(
        hA, w2b, nullptr, nullptr, outA, arena_token, counts, basep, FDIM, DDIM, DDIM / 128, 32);

    combine_k<<<S_TOK * DDIM / 4 / 256, 256, 0, stream>>>(
        outA, b2, topk_e, topk_g, pos_of, (float*)d_out);
}

// Round 4
// 502.992 us; speedup vs baseline: 1.0556x; 1.0371x over previous
//
#include <hip/hip_runtime.h>
#include <hip/hip_bf16.h>
#include <stdint.h>

// MoE FFN: B=2,T=2048,D=1024,F=4096,E=8,K=2. S=4096 tokens, 8192 assignments.
#define S_TOK 4096
#define DDIM  1024
#define FDIM  4096
#define EEXP  8
#define CAP   (S_TOK * 2)         // assignment arena rows (indices clamped < count)

typedef __bf16 bf16x8 __attribute__((ext_vector_type(8)));
typedef float  f32x4  __attribute__((ext_vector_type(4)));
typedef unsigned short us4 __attribute__((ext_vector_type(4)));

__device__ __forceinline__ unsigned short f2bf(float f) {
    union { float f; unsigned u; } v; v.f = f;
    unsigned u = v.u;
    return (unsigned short)((u + 0x7FFFu + ((u >> 16) & 1u)) >> 16);  // RNE
}

// global -> LDS async copy, 16B per lane. LDS dest = wave-uniform base + lane*16.
__device__ __forceinline__ void gload16(const void* g, void* l) {
    auto gp = reinterpret_cast<const __attribute__((address_space(1))) uint32_t*>(
        reinterpret_cast<uintptr_t>(g));
    auto lp = reinterpret_cast<__attribute__((address_space(3))) uint32_t*>(
        static_cast<uint32_t>(reinterpret_cast<uintptr_t>(l)));
    __builtin_amdgcn_global_load_lds(gp, lp, 16, 0, 0);
}

// ---------------- small kernels ----------------

__global__ void zero_k(int* p, int n) {
    int i = threadIdx.x;
    if (i < n) p[i] = 0;
}

__global__ void cvt_bf16(const float* __restrict__ src, unsigned short* __restrict__ dst, int n4) {
    int stride = gridDim.x * blockDim.x;
    for (int i = blockIdx.x * blockDim.x + threadIdx.x; i < n4; i += stride) {
        float4 v = ((const float4*)src)[i];
        us4 o;
        o[0] = f2bf(v.x); o[1] = f2bf(v.y); o[2] = f2bf(v.z); o[3] = f2bf(v.w);
        ((us4*)dst)[i] = o;
    }
}

// Router: one wave per token, fp32 dot products (must match numpy top-2 selection).
// Also emits the bf16 copy of x (fused).
__global__ void router_k(const float* __restrict__ x, const float* __restrict__ gw,
                         unsigned short* __restrict__ xb,
                         int* __restrict__ topk_e, float* __restrict__ topk_g,
                         int* __restrict__ counts) {
    int s = blockIdx.x;
    int l = threadIdx.x;
    const float* xr = x + (size_t)s * DDIM;
    unsigned short* xbr = xb + (size_t)s * DDIM;
    float acc[EEXP];
#pragma unroll
    for (int e = 0; e < EEXP; ++e) acc[e] = 0.f;
    for (int i = 0; i < DDIM; i += 64) {
        float xv = xr[i + l];
        xbr[i + l] = f2bf(xv);
#pragma unroll
        for (int e = 0; e < EEXP; ++e) acc[e] = fmaf(xv, gw[e * DDIM + i + l], acc[e]);
    }
#pragma unroll
    for (int e = 0; e < EEXP; ++e)
        for (int off = 32; off > 0; off >>= 1) acc[e] += __shfl_down(acc[e], off, 64);
    if (l == 0) {
        float v0 = -1e30f, v1 = -1e30f; int i0 = 0, i1 = 0;
#pragma unroll
        for (int e = 0; e < EEXP; ++e) {
            float v = acc[e];
            if (v > v0)      { v1 = v0; i1 = i0; v0 = v; i0 = e; }
            else if (v > v1) { v1 = v;  i1 = e; }
        }
        float t = expf(v1 - v0);
        float d = 1.f + t;
        topk_e[2 * s] = i0; topk_e[2 * s + 1] = i1;
        topk_g[2 * s] = 1.f / d; topk_g[2 * s + 1] = t / d;
        atomicAdd(&counts[i0], 1);
        atomicAdd(&counts[i1], 1);
    }
}

__global__ void scan_k(const int* __restrict__ counts, int* __restrict__ basep) {
    if (threadIdx.x == 0) {
        int b = 0;
        for (int e = 0; e < EEXP; ++e) { basep[e] = b; b += counts[e]; }
    }
}

__global__ void scatter_k(const int* __restrict__ topk_e, int* __restrict__ rankctr,
                          const int* __restrict__ basep, int* __restrict__ arena_token,
                          int* __restrict__ pos_of) {
    int s = blockIdx.x * blockDim.x + threadIdx.x;
    if (s >= S_TOK) return;
#pragma unroll
    for (int t = 0; t < 2; ++t) {
        int e = topk_e[2 * s + t];
        int r = atomicAdd(&rankctr[e], 1);
        int p = basep[e] + r;
        arena_token[p] = s;
        pos_of[2 * s + t] = p;
    }
}

// ---------------- MFMA GEMM: 256x128 tile, BK=64, 8 waves, triple-buffer counted-vmcnt ----
// C[m][n] = sum_k A[m][k] * B[n][k]  (both K-contiguous row-major)
// Schedule (T3+T4): 3 LDS buffers (48KB each: A 32KB rows 0..255 x 128B, B 16KB rows
// 0..127 x 128B). Iter t: reads buf(t%3); stages tile t+2 into buf((t+2)%3) (6 gload16
// per wave); ends with s_waitcnt vmcnt(6) (newest stage group may stay in flight ->
// tile t+1 guaranteed landed for ALL waves at the barrier) + raw s_barrier.
// Race analysis: buf((t+2)%3)'s previous contents (tile t-1) were fully read before the
// PREVIOUS barrier (every wave drains lgkm before its MFMA, which precedes the barrier).
// LDS swizzle (both-sides, rule 21): physical 16B-chunk c_phys = c_log ^ (row&7);
// write side via pre-swizzled global source (lane-pure: row&7 == (tid>>3)&7);
// read side row&7 == l&7 (frag row bases are multiples of 16). 2 lanes/bank = free.
// EPI==1: A rows gathered via arena_token; out = relu(acc+b1) -> hOut bf16.
// EPI==2: A rows contiguous in arena (clamped to count-1; masked at store); out fp32.
template <int EPI>
__global__ __launch_bounds__(512, 2) void moe_gemm(
    const unsigned short* __restrict__ Asrc, const unsigned short* __restrict__ Bw,
    const float* __restrict__ bias, unsigned short* __restrict__ hOut,
    float* __restrict__ fOut, const int* __restrict__ arena_token,
    const int* __restrict__ counts, const int* __restrict__ basep, int Kd, int Nd,
    int ny) {
    // T1: bijective XCD swizzle (gridDim.x % 8 == 0). n-major work order.
    int cpx = gridDim.x >> 3;
    int bid = blockIdx.x;
    int wid = (bid & 7) * cpx + (bid >> 3);
    int my  = wid % ny;
    int ne  = wid / ny;
    int e   = ne % EEXP;
    int n   = ne / EEXP;

    int count = counts[e];
    int m0 = my * 256;
    if (m0 >= count) return;
    int base = basep[e];
    int n0 = n * 128;
    int tid = threadIdx.x, w = tid >> 6, l = tid & 63;

    __shared__ __align__(16) char smem[3 * 49152];

    // ---- staged-source pointers (pre-swizzled k-chunk, lane-pure) ----
    int tid8 = tid >> 3;
    int clog = ((tid & 7) ^ (tid8 & 7)) * 8;   // element offset within 64-wide K-tile
    const unsigned short* pA[4];
    const unsigned short* pB[2];
#pragma unroll
    for (int i = 0; i < 4; ++i) {
        int r = i * 64 + tid8;                  // tile row 0..255
        int gr = m0 + r;
        int rr = (gr < count) ? gr : (count - 1);
        if (EPI == 1) {
            int tok = arena_token[base + rr];
            pA[i] = Asrc + (size_t)tok * Kd + clog;
        } else {
            pA[i] = Asrc + (size_t)(base + rr) * Kd + clog;
        }
    }
#pragma unroll
    for (int j = 0; j < 2; ++j) {
        int r = n0 + j * 64 + tid8;             // B row
        pB[j] = Bw + ((size_t)e * Nd + r) * Kd + clog;
    }

#define STAGE(sb, kt) do {                                            \
        char* ab_ = smem + (sb) * 49152 + w * 1024;                   \
        int ko_ = (kt) << 6;                                          \
        gload16(pA[0] + ko_, ab_);                                    \
        gload16(pA[1] + ko_, ab_ + 8192);                             \
        gload16(pA[2] + ko_, ab_ + 16384);                            \
        gload16(pA[3] + ko_, ab_ + 24576);                            \
        gload16(pB[0] + ko_, ab_ + 32768);                            \
        gload16(pB[1] + ko_, ab_ + 40960);                            \
    } while (0)

    // ---- fragment read addressing ----
    int wm = w >> 2, wn = w & 3;                // 2 (M) x 4 (N) waves
    int lo7 = l & 7, hi = l >> 4;
    int cix[2] = { ((hi ^ lo7) << 4), (((4 + hi) ^ lo7) << 4) };  // swizzled 16B chunk
    const char* Ab0 = smem + (size_t)(wm * 128 + (l & 15)) * 128;
    const char* Bb0 = smem + 32768 + (size_t)(wn * 32 + (l & 15)) * 128;

    f32x4 acc[8][2];
#pragma unroll
    for (int i = 0; i < 8; ++i) {
        acc[i][0] = (f32x4){0.f, 0.f, 0.f, 0.f};
        acc[i][1] = (f32x4){0.f, 0.f, 0.f, 0.f};
    }

    int nt = Kd >> 6;
    STAGE(0, 0);
    STAGE(1, 1);
    asm volatile("s_waitcnt vmcnt(6)" ::: "memory");
    __builtin_amdgcn_s_barrier();
    asm volatile("" ::: "memory");

    int cb = 0, sb = 2;
    for (int t = 0; t < nt; ++t) {
        if (t + 2 < nt) STAGE(sb, t + 2);
        const char* Ab = Ab0 + cb * 49152;
        const char* Bb = Bb0 + cb * 49152;
        bf16x8 af[8][2], bfr[2][2];
#pragma unroll
        for (int mi = 0; mi < 8; ++mi) {
            af[mi][0] = *(const bf16x8*)(Ab + mi * 2048 + cix[0]);
            af[mi][1] = *(const bf16x8*)(Ab + mi * 2048 + cix[1]);
        }
#pragma unroll
        for (int ni = 0; ni < 2; ++ni) {
            bfr[ni][0] = *(const bf16x8*)(Bb + ni * 2048 + cix[0]);
            bfr[ni][1] = *(const bf16x8*)(Bb + ni * 2048 + cix[1]);
        }
#pragma unroll
        for (int kk = 0; kk < 2; ++kk)
#pragma unroll
            for (int mi = 0; mi < 8; ++mi)
#pragma unroll
                for (int ni = 0; ni < 2; ++ni)
                    acc[mi][ni] = __builtin_amdgcn_mfma_f32_16x16x32_bf16(
                        af[mi][kk], bfr[ni][kk], acc[mi][ni], 0, 0, 0);
        if (t + 2 < nt) {
            asm volatile("s_waitcnt vmcnt(6)" ::: "memory");  // tile t+1 landed; t+2 in flight
        } else {
            asm volatile("s_waitcnt vmcnt(0)" ::: "memory");  // tail drain
        }
        __builtin_amdgcn_s_barrier();
        asm volatile("" ::: "memory");
        cb = (cb == 2) ? 0 : cb + 1;
        sb = (sb == 2) ? 0 : sb + 1;
    }
#undef STAGE

    // Epilogue. C/D layout: col = lane&15, row = (lane>>4)*4 + reg  [m89 verified]
#pragma unroll
    for (int mi = 0; mi < 8; ++mi)
#pragma unroll
        for (int ni = 0; ni < 2; ++ni)
#pragma unroll
            for (int r = 0; r < 4; ++r) {
                int rl = wm * 128 + mi * 16 + hi * 4 + r;
                int gr = m0 + rl;
                if (gr < count) {
                    int col = n0 + wn * 32 + ni * 16 + (l & 15);
                    float v = acc[mi][ni][r];
                    if (EPI == 1) {
                        v += bias[e * Nd + col];
                        v = fmaxf(v, 0.f);
                        hOut[(size_t)(base + gr) * Nd + col] = f2bf(v);
                    } else {
                        fOut[(size_t)(base + gr) * Nd + col] = v;
                    }
                }
            }
}

// Deterministic combine: y[s] = g0*(out[p0]+b2[e0]) + g1*(out[p1]+b2[e1])
__global__ void combine_k(const float* __restrict__ outA, const float* __restrict__ b2,
                          const int* __restrict__ topk_e, const float* __restrict__ topk_g,
                          const int* __restrict__ pos_of, float* __restrict__ y) {
    int idx = blockIdx.x * blockDim.x + threadIdx.x;  // S*D/4 threads
    int s = idx >> 8;            // D/4 = 256
    int c = (idx & 255) * 4;
    int e0 = topk_e[2 * s], e1 = topk_e[2 * s + 1];
    float g0 = topk_g[2 * s], g1 = topk_g[2 * s + 1];
    int p0 = pos_of[2 * s], p1 = pos_of[2 * s + 1];
    float4 o0 = *(const float4*)(outA + (size_t)p0 * DDIM + c);
    float4 o1 = *(const float4*)(outA + (size_t)p1 * DDIM + c);
    float4 c0 = *(const float4*)(b2 + (size_t)e0 * DDIM + c);
    float4 c1 = *(const float4*)(b2 + (size_t)e1 * DDIM + c);
    float4 r;
    r.x = g0 * (o0.x + c0.x) + g1 * (o1.x + c1.x);
    r.y = g0 * (o0.y + c0.y) + g1 * (o1.y + c1.y);
    r.z = g0 * (o0.z + c0.z) + g1 * (o1.z + c1.z);
    r.w = g0 * (o0.w + c0.w) + g1 * (o1.w + c1.w);
    *(float4*)(y + (size_t)s * DDIM + c) = r;
}

extern "C" void kernel_launch(void* const* d_in, const int* in_sizes, int n_in,
                              void* d_out, int out_size, void* d_ws, size_t ws_size,
                              hipStream_t stream) {
    const float* x      = (const float*)d_in[0];
    const float* gate_w = (const float*)d_in[1];
    const float* w1     = (const float*)d_in[2];
    const float* b1     = (const float*)d_in[3];
    const float* w2     = (const float*)d_in[4];
    const float* b2     = (const float*)d_in[5];
    // d_in[6] = k (==2), compile-time constant here.

    char* p = (char*)d_ws;
    unsigned short* w1b = (unsigned short*)p; p += (size_t)EEXP * FDIM * DDIM * 2;  // 64 MB
    unsigned short* w2b = (unsigned short*)p; p += (size_t)EEXP * FDIM * DDIM * 2;  // 64 MB
    unsigned short* xb  = (unsigned short*)p; p += (size_t)S_TOK * DDIM * 2;        //  8 MB
    unsigned short* hA  = (unsigned short*)p; p += (size_t)CAP * FDIM * 2;          // 64 MB
    float* outA         = (float*)p;          p += (size_t)CAP * DDIM * 4;          // 32 MB
    int*   topk_e       = (int*)p;            p += S_TOK * 2 * 4;
    float* topk_g       = (float*)p;          p += S_TOK * 2 * 4;
    int*   pos_of       = (int*)p;            p += S_TOK * 2 * 4;
    int*   arena_token  = (int*)p;            p += CAP * 4;
    int*   counts       = (int*)p;            p += 64;
    int*   rankctr      = (int*)p;            p += 64;
    int*   basep        = (int*)p;            p += 64;
    (void)ws_size; (void)in_sizes; (void)n_in; (void)out_size;

    zero_k<<<1, 64, 0, stream>>>(counts, 48);  // counts + rankctr + basep (contiguous)

    cvt_bf16<<<2048, 256, 0, stream>>>(w1, w1b, EEXP * FDIM * DDIM / 4);
    cvt_bf16<<<2048, 256, 0, stream>>>(w2, w2b, EEXP * FDIM * DDIM / 4);

    router_k<<<S_TOK, 64, 0, stream>>>(x, gate_w, xb, topk_e, topk_g, counts);
    scan_k<<<1, 1, 0, stream>>>(counts, basep);
    scatter_k<<<S_TOK / 256, 256, 0, stream>>>(topk_e, rankctr, basep, arena_token, pos_of);

    // ny=16 covers worst-case count=4096 (16 m-tiles of 256); inactive tiles early-exit.
    // Grid = nx * 16 * E, divisible by 8 for the XCD swizzle.
    moe_gemm<1><<<dim3((FDIM / 128) * 16 * EEXP), 512, 0, stream>>>(
        xb, w1b, b1, hA, nullptr, arena_token, counts, basep, DDIM, FDIM, 16);
    moe_gemm<2><<<dim3((DDIM / 128) * 16 * EEXP), 512, 0, stream>>>(
        hA, w2b, nullptr, nullptr, outA, arena_token, counts, basep, FDIM, DDIM, 16);

    combine_k<<<S_TOK * DDIM / 4 / 256, 256, 0, stream>>>(
        outA, b2, topk_e, topk_g, pos_of, (float*)d_out);
}

// Round 6
// 473.140 us; speedup vs baseline: 1.1222x; 1.0631x over previous
//
#include <hip/hip_runtime.h>
#include <hip/hip_bf16.h>
#include <stdint.h>

// MoE FFN: B=2,T=2048,D=1024,F=4096,E=8,K=2. S=4096 tokens, 8192 assignments.
#define S_TOK 4096
#define DDIM  1024
#define FDIM  4096
#define EEXP  8
#define CAP   (S_TOK * 2)

typedef __bf16 bf16x8 __attribute__((ext_vector_type(8)));
typedef float  f32x4  __attribute__((ext_vector_type(4)));
typedef unsigned short us4 __attribute__((ext_vector_type(4)));

__device__ __forceinline__ unsigned short f2bf(float f) {
    union { float f; unsigned u; } v; v.f = f;
    unsigned u = v.u;
    return (unsigned short)((u + 0x7FFFu + ((u >> 16) & 1u)) >> 16);  // RNE
}

__device__ __forceinline__ void gload16(const void* g, void* l) {
    auto gp = reinterpret_cast<const __attribute__((address_space(1))) uint32_t*>(
        reinterpret_cast<uintptr_t>(g));
    auto lp = reinterpret_cast<__attribute__((address_space(3))) uint32_t*>(
        static_cast<uint32_t>(reinterpret_cast<uintptr_t>(l)));
    __builtin_amdgcn_global_load_lds(gp, lp, 16, 0, 0);
}

// ---------------- small kernels ----------------

__global__ void zero_k(int* p, int n) {
    int i = threadIdx.x;
    if (i < n) p[i] = 0;
}

__global__ void cvt_bf16(const float* __restrict__ src, unsigned short* __restrict__ dst, int n4) {
    int stride = gridDim.x * blockDim.x;
    for (int i = blockIdx.x * blockDim.x + threadIdx.x; i < n4; i += stride) {
        float4 v = ((const float4*)src)[i];
        us4 o;
        o[0] = f2bf(v.x); o[1] = f2bf(v.y); o[2] = f2bf(v.z); o[3] = f2bf(v.w);
        ((us4*)dst)[i] = o;
    }
}

// Router: one wave per token, fp32 (must match numpy top-2 selection). Fused x->bf16.
__global__ void router_k(const float* __restrict__ x, const float* __restrict__ gw,
                         unsigned short* __restrict__ xb,
                         int* __restrict__ topk_e, float* __restrict__ topk_g,
                         int* __restrict__ counts) {
    int s = blockIdx.x;
    int l = threadIdx.x;
    const float* xr = x + (size_t)s * DDIM;
    unsigned short* xbr = xb + (size_t)s * DDIM;
    float acc[EEXP];
#pragma unroll
    for (int e = 0; e < EEXP; ++e) acc[e] = 0.f;
    for (int i = 0; i < DDIM; i += 64) {
        float xv = xr[i + l];
        xbr[i + l] = f2bf(xv);
#pragma unroll
        for (int e = 0; e < EEXP; ++e) acc[e] = fmaf(xv, gw[e * DDIM + i + l], acc[e]);
    }
#pragma unroll
    for (int e = 0; e < EEXP; ++e)
        for (int off = 32; off > 0; off >>= 1) acc[e] += __shfl_down(acc[e], off, 64);
    if (l == 0) {
        float v0 = -1e30f, v1 = -1e30f; int i0 = 0, i1 = 0;
#pragma unroll
        for (int e = 0; e < EEXP; ++e) {
            float v = acc[e];
            if (v > v0)      { v1 = v0; i1 = i0; v0 = v; i0 = e; }
            else if (v > v1) { v1 = v;  i1 = e; }
        }
        float t = expf(v1 - v0);
        float d = 1.f + t;
        topk_e[2 * s] = i0; topk_e[2 * s + 1] = i1;
        topk_g[2 * s] = 1.f / d; topk_g[2 * s + 1] = t / d;
        atomicAdd(&counts[i0], 1);
        atomicAdd(&counts[i1], 1);
    }
}

__global__ void scan_k(const int* __restrict__ counts, int* __restrict__ basep) {
    if (threadIdx.x == 0) {
        int b = 0;
        for (int e = 0; e < EEXP; ++e) { basep[e] = b; b += counts[e]; }
    }
}

__global__ void scatter_k(const int* __restrict__ topk_e, int* __restrict__ rankctr,
                          const int* __restrict__ basep, int* __restrict__ arena_token,
                          int* __restrict__ pos_of) {
    int s = blockIdx.x * blockDim.x + threadIdx.x;
    if (s >= S_TOK) return;
#pragma unroll
    for (int t = 0; t < 2; ++t) {
        int e = topk_e[2 * s + t];
        int r = atomicAdd(&rankctr[e], 1);
        int p = basep[e] + r;
        arena_token[p] = s;
        pos_of[2 * s + t] = p;
    }
}

// ---------------- MFMA GEMM: 256x256 tile, BK=64, 8 waves (2Mx4N), wave-out 128x64 ----
// C[m][n] = sum_k A[m][k]*B[n][k]. LDS 128KB: 2 slots x {A[kk][256][32k] 32K, B[kk][256][32k] 32K}.
// Swizzle (both-sides): chunk_phys = chunk_log ^ ((row>>1)&3). Write via pre-swizzled global
// source (lane-pure: (tid&3)^((tid>>3)&3)); read chunk = (l>>4)^((l>>1)&3). 2 lanes/bank = free.
// Schedule per K-tile t (slot s=t&1), 4 phases:
//  P0: STAGE(t+1 h1 -> s^1 kk1); read B0,A[rh0] kk0; 16 MFMA
//  P1: read A[rh1] kk0; 16 MFMA;   WAIT{vmcnt(8) lgkm(0)} + s_barrier
//  P2: STAGE(t+2 h0 -> s kk0); read B1,A[rh0] kk1; 16 MFMA
//  P3: read A[rh1] kk1; 16 MFMA;   WAIT{vmcnt(8) lgkm(0)} + s_barrier
// Per-wave ledger: enter tile t with [t.kk1, t+1.kk0] = 8 outstanding; P0 +4; P1-end
// vmcnt(8) retires t.kk1 (consumed P2/P3); P2 +4; P3-end retires t+1.kk0. Each wave
// waits its OWN counter pre-barrier; barrier joins -> union guarantee across waves.
// Tail: vmcnt 8/4/0 as lookahead shrinks.
template <int EPI>
__global__ __launch_bounds__(512, 2) void moe_gemm(
    const unsigned short* __restrict__ Asrc, const unsigned short* __restrict__ Bw,
    const float* __restrict__ bias, unsigned short* __restrict__ hOut,
    float* __restrict__ fOut, const int* __restrict__ arena_token,
    const int* __restrict__ counts, const int* __restrict__ basep,
    int Kd, int Nd, int ny, int Klen) {
    // T1: bijective XCD swizzle (gridDim.x % 8 == 0). n-major work order, K-split outermost.
    int cpx = gridDim.x >> 3;
    int bid = blockIdx.x;
    int wid = (bid & 7) * cpx + (bid >> 3);
    int per = (Nd >> 8) * ny * EEXP;
    int ks  = wid / per;
    int rem = wid - ks * per;
    int my  = rem % ny;
    int ne  = rem / ny;
    int e   = ne % EEXP;
    int n   = ne / EEXP;

    int count = counts[e];
    int m0 = my * 256;
    if (m0 >= count) return;
    int base = basep[e];
    int n0 = n * 256;
    int kbase = ks * Klen;
    int tid = threadIdx.x, w = tid >> 6, l = tid & 63;

    // K-split partial output buffer (EPI==2): partial ks lives at +ks*CAP*DDIM.
    float* fOutP = fOut + (size_t)ks * CAP * DDIM;   // <-- r5 bug fix (both ks wrote partial 0)

    __shared__ __align__(16) char smem[131072];

    // ---- stage source pointers (pre-swizzled k-chunk, lane-pure) ----
    int tr = tid >> 2;                               // 0..127
    int clog = ((tid & 3) ^ ((tid >> 3) & 3)) * 8;   // element offset
    const unsigned short *pA0, *pA1, *pB0, *pB1;
    {
        int r0 = m0 + tr, r1 = m0 + 128 + tr;
        int c0 = (r0 < count) ? r0 : (count - 1);
        int c1 = (r1 < count) ? r1 : (count - 1);
        if (EPI == 1) {
            pA0 = Asrc + (size_t)arena_token[base + c0] * Kd + kbase + clog;
            pA1 = Asrc + (size_t)arena_token[base + c1] * Kd + kbase + clog;
        } else {
            pA0 = Asrc + (size_t)(base + c0) * Kd + kbase + clog;
            pA1 = Asrc + (size_t)(base + c1) * Kd + kbase + clog;
        }
        pB0 = Bw + ((size_t)e * Nd + n0 + tr) * Kd + kbase + clog;
        pB1 = Bw + ((size_t)e * Nd + n0 + 128 + tr) * Kd + kbase + clog;
    }

#define STAGEH(slot, kk, T) do {                                       \
        int lb_ = (slot) * 65536 + (kk) * 16384 + w * 1024;            \
        size_t ko_ = (size_t)(T) * 64 + (size_t)(kk) * 32;             \
        gload16(pA0 + ko_, smem + lb_);                                \
        gload16(pA1 + ko_, smem + lb_ + 8192);                         \
        gload16(pB0 + ko_, smem + lb_ + 32768);                        \
        gload16(pB1 + ko_, smem + lb_ + 40960);                        \
    } while (0)

#define WAITB(vm) do {                                                         \
        asm volatile("s_waitcnt vmcnt(" #vm ") lgkmcnt(0)" ::: "memory");      \
        __builtin_amdgcn_sched_barrier(0);                                     \
        __builtin_amdgcn_s_barrier();                                          \
        asm volatile("" ::: "memory");                                         \
    } while (0)

    // ---- fragment read addressing ----
    int wm = w >> 2, wn = w & 3;                 // 2(M) x 4(N) waves
    int hi = l >> 4;
    int rdc = ((hi ^ ((l >> 1) & 3)) << 4);      // swizzled 16B chunk (lane-pure)
    const char* Ar = smem + (size_t)(wm * 128 + (l & 15)) * 64 + rdc;
    const char* Br = smem + 32768 + (size_t)(wn * 64 + (l & 15)) * 64 + rdc;

    f32x4 acc[8][4];
#pragma unroll
    for (int i = 0; i < 8; ++i)
#pragma unroll
        for (int j = 0; j < 4; ++j) acc[i][j] = (f32x4){0.f, 0.f, 0.f, 0.f};

    int nt = Klen >> 6;
    // prologue: t0 kk0, t0 kk1, t1 kk0
    STAGEH(0, 0, 0);
    STAGEH(0, 1, 0);
    STAGEH(1, 0, 1);
    asm volatile("s_waitcnt vmcnt(8)" ::: "memory");
    __builtin_amdgcn_sched_barrier(0);
    __builtin_amdgcn_s_barrier();
    asm volatile("" ::: "memory");

    for (int t = 0; t < nt; ++t) {
        int sl = (t & 1) * 65536;
        const char* Ab = Ar + sl;
        const char* Bb = Br + sl;
        bf16x8 bf[4], afr[4];
        // ---- P0: rh0, kk0 ----
        if (t + 1 < nt) STAGEH((t & 1) ^ 1, 1, t + 1);
#pragma unroll
        for (int ni = 0; ni < 4; ++ni) bf[ni] = *(const bf16x8*)(Bb + ni * 1024);
#pragma unroll
        for (int mi = 0; mi < 4; ++mi) afr[mi] = *(const bf16x8*)(Ab + mi * 1024);
        __builtin_amdgcn_s_setprio(1);
#pragma unroll
        for (int mi = 0; mi < 4; ++mi)
#pragma unroll
            for (int ni = 0; ni < 4; ++ni)
                acc[mi][ni] = __builtin_amdgcn_mfma_f32_16x16x32_bf16(afr[mi], bf[ni], acc[mi][ni], 0, 0, 0);
        __builtin_amdgcn_s_setprio(0);
        // ---- P1: rh1, kk0 ----
#pragma unroll
        for (int mi = 0; mi < 4; ++mi) afr[mi] = *(const bf16x8*)(Ab + 4096 + mi * 1024);
        __builtin_amdgcn_s_setprio(1);
#pragma unroll
        for (int mi = 0; mi < 4; ++mi)
#pragma unroll
            for (int ni = 0; ni < 4; ++ni)
                acc[4 + mi][ni] = __builtin_amdgcn_mfma_f32_16x16x32_bf16(afr[mi], bf[ni], acc[4 + mi][ni], 0, 0, 0);
        __builtin_amdgcn_s_setprio(0);
        if (t + 1 < nt) WAITB(8); else WAITB(0);
        // ---- P2: rh0, kk1 ----
        if (t + 2 < nt) STAGEH(t & 1, 0, t + 2);
#pragma unroll
        for (int ni = 0; ni < 4; ++ni) bf[ni] = *(const bf16x8*)(Bb + 16384 + ni * 1024);
#pragma unroll
        for (int mi = 0; mi < 4; ++mi) afr[mi] = *(const bf16x8*)(Ab + 16384 + mi * 1024);
        __builtin_amdgcn_s_setprio(1);
#pragma unroll
        for (int mi = 0; mi < 4; ++mi)
#pragma unroll
            for (int ni = 0; ni < 4; ++ni)
                acc[mi][ni] = __builtin_amdgcn_mfma_f32_16x16x32_bf16(afr[mi], bf[ni], acc[mi][ni], 0, 0, 0);
        __builtin_amdgcn_s_setprio(0);
        // ---- P3: rh1, kk1 ----
#pragma unroll
        for (int mi = 0; mi < 4; ++mi) afr[mi] = *(const bf16x8*)(Ab + 20480 + mi * 1024);
        __builtin_amdgcn_s_setprio(1);
#pragma unroll
        for (int mi = 0; mi < 4; ++mi)
#pragma unroll
            for (int ni = 0; ni < 4; ++ni)
                acc[4 + mi][ni] = __builtin_amdgcn_mfma_f32_16x16x32_bf16(afr[mi], bf[ni], acc[4 + mi][ni], 0, 0, 0);
        __builtin_amdgcn_s_setprio(0);
        if (t + 2 < nt) WAITB(8);
        else if (t + 1 < nt) WAITB(4);
        else WAITB(0);
    }
#undef STAGEH
#undef WAITB

    // Epilogue. C/D layout: col = lane&15, row = (lane>>4)*4 + reg  [m89 verified]
#pragma unroll
    for (int rf = 0; rf < 8; ++rf)
#pragma unroll
        for (int ni = 0; ni < 4; ++ni)
#pragma unroll
            for (int r = 0; r < 4; ++r) {
                int rl = wm * 128 + rf * 16 + hi * 4 + r;
                int gr = m0 + rl;
                if (gr < count) {
                    int col = n0 + wn * 64 + ni * 16 + (l & 15);
                    float v = acc[rf][ni][r];
                    if (EPI == 1) {
                        v += bias[e * Nd + col];
                        v = fmaxf(v, 0.f);
                        hOut[(size_t)(base + gr) * Nd + col] = f2bf(v);
                    } else {
                        fOutP[(size_t)(base + gr) * Nd + col] = v;
                    }
                }
            }
}

// Deterministic combine with 2 K-split partials:
// y[s] = g0*(P0[p0]+P1[p0]+b2[e0]) + g1*(P0[p1]+P1[p1]+b2[e1])
__global__ void combine_k(const float* __restrict__ outP, const float* __restrict__ b2,
                          const int* __restrict__ topk_e, const float* __restrict__ topk_g,
                          const int* __restrict__ pos_of, float* __restrict__ y) {
    int idx = blockIdx.x * blockDim.x + threadIdx.x;  // S*D/4 threads
    int s = idx >> 8;            // D/4 = 256
    int c = (idx & 255) * 4;
    int e0 = topk_e[2 * s], e1 = topk_e[2 * s + 1];
    float g0 = topk_g[2 * s], g1 = topk_g[2 * s + 1];
    int p0 = pos_of[2 * s], p1 = pos_of[2 * s + 1];
    const float* P1 = outP + (size_t)CAP * DDIM;
    float4 a0 = *(const float4*)(outP + (size_t)p0 * DDIM + c);
    float4 a1 = *(const float4*)(P1   + (size_t)p0 * DDIM + c);
    float4 b0v = *(const float4*)(outP + (size_t)p1 * DDIM + c);
    float4 b1v = *(const float4*)(P1   + (size_t)p1 * DDIM + c);
    float4 c0 = *(const float4*)(b2 + (size_t)e0 * DDIM + c);
    float4 c1 = *(const float4*)(b2 + (size_t)e1 * DDIM + c);
    float4 r;
    r.x = g0 * (a0.x + a1.x + c0.x) + g1 * (b0v.x + b1v.x + c1.x);
    r.y = g0 * (a0.y + a1.y + c0.y) + g1 * (b0v.y + b1v.y + c1.y);
    r.z = g0 * (a0.z + a1.z + c0.z) + g1 * (b0v.z + b1v.z + c1.z);
    r.w = g0 * (a0.w + a1.w + c0.w) + g1 * (b0v.w + b1v.w + c1.w);
    *(float4*)(y + (size_t)s * DDIM + c) = r;
}

extern "C" void kernel_launch(void* const* d_in, const int* in_sizes, int n_in,
                              void* d_out, int out_size, void* d_ws, size_t ws_size,
                              hipStream_t stream) {
    const float* x      = (const float*)d_in[0];
    const float* gate_w = (const float*)d_in[1];
    const float* w1     = (const float*)d_in[2];
    const float* b1     = (const float*)d_in[3];
    const float* w2     = (const float*)d_in[4];
    const float* b2     = (const float*)d_in[5];

    char* p = (char*)d_ws;
    unsigned short* w1b = (unsigned short*)p;   // 64 MB; reused as outP (2x32MB partials) after GEMM1
    float* outP         = (float*)p;            p += (size_t)EEXP * FDIM * DDIM * 2;
    unsigned short* w2b = (unsigned short*)p;   p += (size_t)EEXP * FDIM * DDIM * 2;  // 64 MB
    unsigned short* xb  = (unsigned short*)p;   p += (size_t)S_TOK * DDIM * 2;        //  8 MB
    unsigned short* hA  = (unsigned short*)p;   p += (size_t)CAP * FDIM * 2;          // 64 MB
    int*   topk_e       = (int*)p;              p += S_TOK * 2 * 4;
    float* topk_g       = (float*)p;            p += S_TOK * 2 * 4;
    int*   pos_of       = (int*)p;              p += S_TOK * 2 * 4;
    int*   arena_token  = (int*)p;              p += CAP * 4;
    int*   counts       = (int*)p;              p += 64;
    int*   rankctr      = (int*)p;              p += 64;
    int*   basep        = (int*)p;              p += 64;
    (void)ws_size; (void)in_sizes; (void)n_in; (void)out_size;

    zero_k<<<1, 64, 0, stream>>>(counts, 48);

    cvt_bf16<<<2048, 256, 0, stream>>>(w1, w1b, EEXP * FDIM * DDIM / 4);
    cvt_bf16<<<2048, 256, 0, stream>>>(w2, w2b, EEXP * FDIM * DDIM / 4);

    router_k<<<S_TOK, 64, 0, stream>>>(x, gate_w, xb, topk_e, topk_g, counts);
    scan_k<<<1, 1, 0, stream>>>(counts, basep);
    scatter_k<<<S_TOK / 256, 256, 0, stream>>>(topk_e, rankctr, basep, arena_token, pos_of);

    // GEMM1: A = gathered xb (K=1024), B = w1b (F=4096), out = hA bf16 (relu+b1).
    // grid = nx(16) * ny(16) * E(8) = 2048 (div by 8 for XCD swizzle)
    moe_gemm<1><<<dim3((FDIM / 256) * 16 * EEXP), 512, 0, stream>>>(
        xb, w1b, b1, hA, nullptr, arena_token, counts, basep, DDIM, FDIM, 16, DDIM);
    // GEMM2: A = hA (K=4096, split 2), B = w2b (D=1024), out = outP fp32 partials.
    // grid = nx(4) * ny(16) * E(8) * KS(2) = 1024
    moe_gemm<2><<<dim3((DDIM / 256) * 16 * EEXP * 2), 512, 0, stream>>>(
        hA, w2b, nullptr, nullptr, outP, arena_token, counts, basep, FDIM, DDIM, 16, FDIM / 2);

    combine_k<<<S_TOK * DDIM / 4 / 256, 256, 0, stream>>>(
        outP, b2, topk_e, topk_g, pos_of, (float*)d_out);
}